// Round 3
// baseline (613.709 us; speedup 1.0000x reference)
//
#include <hip/hip_runtime.h>
#include <cstdint>
#include <cstddef>

#define BATCH 8
#define SEQ   2048
#define DM    1024
#define DE    2048   // D_MODEL*EXPAND
#define DSZ   256    // D_STATE
#define MROWS (BATCH*SEQ)  // 16384

typedef __bf16 bf16;
typedef __bf16 bf16x8 __attribute__((ext_vector_type(8)));
typedef _Float16 f16;
typedef _Float16 f16x8 __attribute__((ext_vector_type(8)));
typedef float  f32x4  __attribute__((ext_vector_type(4)));

// async global->LDS, 16B per lane (global_load_lds_dwordx4).
__device__ __forceinline__ void glds16(const void* gp, void* lp) {
  __builtin_amdgcn_global_load_lds(
      (const __attribute__((address_space(1))) void*)gp,
      (__attribute__((address_space(3))) void*)lp, 16, 0, 0);
}

__device__ __forceinline__ float silu_f(float x) {
  return x * __builtin_amdgcn_rcpf(1.0f + __expf(-x));
}

// ---------------- transpose + split: in[R][C] fp32 -> hi/lo [C][R] f16 ----------------
__global__ void transpose_split_k(const float* __restrict__ in, f16* __restrict__ oh,
                                  f16* __restrict__ ol, int R, int C) {
  __shared__ float tile[32][33];
  const int c0 = blockIdx.x * 32, r0 = blockIdx.y * 32;
  const int tx = threadIdx.x, ty = threadIdx.y; // 32 x 8
  #pragma unroll
  for (int i = 0; i < 4; ++i)
    tile[ty + i*8][tx] = in[(size_t)(r0 + ty + i*8) * C + c0 + tx];
  __syncthreads();
  #pragma unroll
  for (int i = 0; i < 4; ++i) {
    float v = tile[tx][ty + i*8];
    f16 h = (f16)v;
    size_t idx = (size_t)(c0 + ty + i*8) * R + r0 + tx;
    oh[idx] = h;
    ol[idx] = (f16)(v - (float)h);
  }
}

// ---------------- transpose + cast to bf16 ----------------
__global__ void transpose_cast_k(const float* __restrict__ in, bf16* __restrict__ out, int R, int C) {
  __shared__ float tile[32][33];
  const int c0 = blockIdx.x * 32, r0 = blockIdx.y * 32;
  const int tx = threadIdx.x, ty = threadIdx.y;
  #pragma unroll
  for (int i = 0; i < 4; ++i)
    tile[ty + i*8][tx] = in[(size_t)(r0 + ty + i*8) * C + c0 + tx];
  __syncthreads();
  #pragma unroll
  for (int i = 0; i < 4; ++i)
    out[(size_t)(c0 + ty + i*8) * R + r0 + tx] = (bf16)tile[tx][ty + i*8];
}

// ---------------- GEMM1: xproj = silu(x @ W_in + b), split-precision ----------------
// A fp32 [M][1024], Bt hi/lo f16 [2048][1024]. Out: hi/lo f16 [M][2048].
// A staged fp32 (kq-major LDS layout), split to hi/lo f16 in-register; 3 MFMAs/frag.
__global__ __launch_bounds__(256) void gemm1_k(const float* __restrict__ A,
                                               const f16* __restrict__ Bth,
                                               const f16* __restrict__ Btl,
                                               const float* __restrict__ bias,
                                               f16* __restrict__ Ch, f16* __restrict__ Cl) {
  const int K = 1024, N = 2048;
  extern __shared__ char smraw[];
  float* sA  = (float*)smraw;          // 16KB: idx = kq*1024 + m*8 + kj (kq=k>>3)
  f16*   sBh = (f16*)(smraw + 16384);  // 8KB: [n][32]
  f16*   sBl = (f16*)(smraw + 24576);  // 8KB

  const int tid = threadIdx.x;
  const int w = tid >> 6, l = tid & 63;
  const int bm = blockIdx.y * 128, bn = blockIdx.x * 128;
  const int wm = (w >> 1) * 64, wn = (w & 1) * 64;
  const int lr = l & 15, lq = l >> 4;

  // A staging: 1024 16B-chunks; c bits: [0]=half, [7:1]=m, [9:8]=kq
  const float* pA[4]; float* dA[4];
  #pragma unroll
  for (int p = 0; p < 4; ++p) {
    const int c = p * 256 + tid;
    const int kq = c >> 8, m = (c >> 1) & 127, half = c & 1;
    pA[p] = A + (size_t)(bm + m) * K + kq * 8 + half * 4;
    dA[p] = sA + (size_t)c * 4;
  }
  // B staging: 512 chunks each; c bits: [1:0]=k8, [8:2]=n
  const f16* pBh[2]; const f16* pBl[2]; f16* dBh[2]; f16* dBl[2];
  #pragma unroll
  for (int p = 0; p < 2; ++p) {
    const int c = p * 256 + tid;
    const int n = c >> 2, k8 = c & 3;
    pBh[p] = Bth + (size_t)(bn + n) * K + k8 * 8;
    pBl[p] = Btl + (size_t)(bn + n) * K + k8 * 8;
    dBh[p] = sBh + (size_t)c * 8;
    dBl[p] = sBl + (size_t)c * 8;
  }

  int offA[4], offB[4];
  #pragma unroll
  for (int i = 0; i < 4; ++i) {
    offA[i] = lq * 1024 + (wm + i*16 + lr) * 8;     // fp32 elements
    offB[i] = (wn + i*16 + lr) * 32 + lq * 8;       // f16 elements
  }

  f32x4 acc[4][4] = {};

  for (int kk = 0; kk < K; kk += 32) {
    __syncthreads();
    #pragma unroll
    for (int p = 0; p < 4; ++p) { glds16(pA[p], dA[p]); pA[p] += 32; }
    #pragma unroll
    for (int p = 0; p < 2; ++p) {
      glds16(pBh[p], dBh[p]); pBh[p] += 32;
      glds16(pBl[p], dBl[p]); pBl[p] += 32;
    }
    asm volatile("s_waitcnt vmcnt(0)" ::: "memory");
    __syncthreads();

    f16x8 ahf[4], alf[4], bhf[4], blf[4];
    #pragma unroll
    for (int i = 0; i < 4; ++i) {
      f32x4 a0 = *(const f32x4*)(sA + offA[i]);
      f32x4 a1 = *(const f32x4*)(sA + offA[i] + 4);
      #pragma unroll
      for (int j = 0; j < 4; ++j) {
        float v0 = a0[j], v1 = a1[j];
        f16 h0 = (f16)v0, h1 = (f16)v1;
        ahf[i][j]   = h0; alf[i][j]   = (f16)(v0 - (float)h0);
        ahf[i][4+j] = h1; alf[i][4+j] = (f16)(v1 - (float)h1);
      }
    }
    #pragma unroll
    for (int j = 0; j < 4; ++j) {
      bhf[j] = *(const f16x8*)(sBh + offB[j]);
      blf[j] = *(const f16x8*)(sBl + offB[j]);
    }
    #pragma unroll
    for (int i = 0; i < 4; ++i)
      #pragma unroll
      for (int j = 0; j < 4; ++j) {
        acc[i][j] = __builtin_amdgcn_mfma_f32_16x16x32_f16(ahf[i], bhf[j], acc[i][j], 0, 0, 0);
        acc[i][j] = __builtin_amdgcn_mfma_f32_16x16x32_f16(ahf[i], blf[j], acc[i][j], 0, 0, 0);
        acc[i][j] = __builtin_amdgcn_mfma_f32_16x16x32_f16(alf[i], bhf[j], acc[i][j], 0, 0, 0);
      }
  }

  // epilogue: silu, split to hi/lo f16
  #pragma unroll
  for (int j = 0; j < 4; ++j) {
    const int col = bn + wn + j*16 + lr;
    const float bv = bias[col];
    #pragma unroll
    for (int i = 0; i < 4; ++i)
      #pragma unroll
      for (int r = 0; r < 4; ++r) {
        const int row = bm + wm + i*16 + lq*4 + r;
        const float s = silu_f(acc[i][j][r] + bv);
        const f16 h = (f16)s;
        const size_t idx = (size_t)row * N + col;
        Ch[idx] = h;
        Cl[idx] = (f16)(s - (float)h);
      }
  }
}

// ---------------- GEMM2: upd = xproj @ W_state + b, split-precision ----------------
// A hi/lo f16 [M][K], Bt hi/lo f16 [N][K]. Out fp32 [M][N].
__global__ __launch_bounds__(256) void gemm2_k(const f16* __restrict__ Ah, const f16* __restrict__ Al,
                                               const f16* __restrict__ Bh, const f16* __restrict__ Bl,
                                               const float* __restrict__ bias,
                                               float* __restrict__ C, int N, int K) {
  extern __shared__ char smraw[];
  f16* sAh = (f16*)smraw;               // 8KB each, [r][32] tiles
  f16* sAl = (f16*)(smraw + 8192);
  f16* sBh = (f16*)(smraw + 16384);
  f16* sBl = (f16*)(smraw + 24576);

  const int tid = threadIdx.x;
  const int w = tid >> 6, l = tid & 63;
  const int bm = blockIdx.y * 128, bn = blockIdx.x * 128;
  const int wm = (w >> 1) * 64, wn = (w & 1) * 64;
  const int lr = l & 15, lq = l >> 4;

  const f16 *pAh[2], *pAl[2], *pBh[2], *pBl[2];
  f16 *dAh[2], *dAl[2], *dBh[2], *dBl[2];
  #pragma unroll
  for (int p = 0; p < 2; ++p) {
    const int c = p * 256 + tid;
    const int r = c >> 2, k8 = c & 3;
    pAh[p] = Ah + (size_t)(bm + r) * K + k8 * 8;
    pAl[p] = Al + (size_t)(bm + r) * K + k8 * 8;
    pBh[p] = Bh + (size_t)(bn + r) * K + k8 * 8;
    pBl[p] = Bl + (size_t)(bn + r) * K + k8 * 8;
    dAh[p] = sAh + (size_t)c * 8; dAl[p] = sAl + (size_t)c * 8;
    dBh[p] = sBh + (size_t)c * 8; dBl[p] = sBl + (size_t)c * 8;
  }

  int offA[4], offB[4];
  #pragma unroll
  for (int i = 0; i < 4; ++i) {
    offA[i] = (wm + i*16 + lr) * 32 + lq * 8;
    offB[i] = (wn + i*16 + lr) * 32 + lq * 8;
  }

  f32x4 acc[4][4] = {};

  for (int kk = 0; kk < K; kk += 32) {
    __syncthreads();
    #pragma unroll
    for (int p = 0; p < 2; ++p) {
      glds16(pAh[p], dAh[p]); pAh[p] += 32;
      glds16(pAl[p], dAl[p]); pAl[p] += 32;
      glds16(pBh[p], dBh[p]); pBh[p] += 32;
      glds16(pBl[p], dBl[p]); pBl[p] += 32;
    }
    asm volatile("s_waitcnt vmcnt(0)" ::: "memory");
    __syncthreads();

    f16x8 ahf[4], alf[4], bhf[4], blf[4];
    #pragma unroll
    for (int i = 0; i < 4; ++i) {
      ahf[i] = *(const f16x8*)(sAh + offA[i]);
      alf[i] = *(const f16x8*)(sAl + offA[i]);
    }
    #pragma unroll
    for (int j = 0; j < 4; ++j) {
      bhf[j] = *(const f16x8*)(sBh + offB[j]);
      blf[j] = *(const f16x8*)(sBl + offB[j]);
    }
    #pragma unroll
    for (int i = 0; i < 4; ++i)
      #pragma unroll
      for (int j = 0; j < 4; ++j) {
        acc[i][j] = __builtin_amdgcn_mfma_f32_16x16x32_f16(ahf[i], bhf[j], acc[i][j], 0, 0, 0);
        acc[i][j] = __builtin_amdgcn_mfma_f32_16x16x32_f16(ahf[i], blf[j], acc[i][j], 0, 0, 0);
        acc[i][j] = __builtin_amdgcn_mfma_f32_16x16x32_f16(alf[i], bhf[j], acc[i][j], 0, 0, 0);
      }
  }

  #pragma unroll
  for (int j = 0; j < 4; ++j) {
    const int col = bn + wn + j*16 + lr;
    const float bv = bias[col];
    #pragma unroll
    for (int i = 0; i < 4; ++i)
      #pragma unroll
      for (int r = 0; r < 4; ++r) {
        const int row = bm + wm + i*16 + lq*4 + r;
        C[(size_t)row * N + col] = acc[i][j][r] + bv;
      }
  }
}

// ---------------- GEMM3 (post-scan, bf16 is fine): C = A @ Bt^T + bias, fp32 out ----------------
__global__ __launch_bounds__(256) void gemm3_k(const bf16* __restrict__ A,
                                               const bf16* __restrict__ Bt,
                                               const float* __restrict__ bias,
                                               float* __restrict__ C, int N, int K) {
  extern __shared__ char smraw[];
  bf16* sA = (bf16*)smraw;
  bf16* sB = (bf16*)(smraw + 8192);

  const int tid = threadIdx.x;
  const int w = tid >> 6, l = tid & 63;
  const int bm = blockIdx.y * 128, bn = blockIdx.x * 128;
  const int wm = (w >> 1) * 64, wn = (w & 1) * 64;
  const int lr = l & 15, lq = l >> 4;

  const bf16* pA[2]; const bf16* pB[2];
  bf16* ldsA[2]; bf16* ldsB[2];
  #pragma unroll
  for (int p = 0; p < 2; ++p) {
    const int c = (p*4 + w)*64 + l;
    pA[p] = A  + (size_t)(bm + (c >> 2)) * K + (c & 3) * 8;
    pB[p] = Bt + (size_t)(bn + (c >> 2)) * K + (c & 3) * 8;
    ldsA[p] = sA + (size_t)c * 8;
    ldsB[p] = sB + (size_t)c * 8;
  }

  int offA[4], offB[4];
  #pragma unroll
  for (int i = 0; i < 4; ++i) {
    offA[i] = (wm + i*16 + lr) * 32 + lq * 8;
    offB[i] = (wn + i*16 + lr) * 32 + lq * 8;
  }

  f32x4 acc[4][4] = {};

  for (int kk = 0; kk < K; kk += 32) {
    __syncthreads();
    glds16(pA[0], ldsA[0]); glds16(pA[1], ldsA[1]);
    glds16(pB[0], ldsB[0]); glds16(pB[1], ldsB[1]);
    pA[0] += 32; pA[1] += 32; pB[0] += 32; pB[1] += 32;
    asm volatile("s_waitcnt vmcnt(0)" ::: "memory");
    __syncthreads();

    bf16x8 af[4], bfr[4];
    #pragma unroll
    for (int i = 0; i < 4; ++i) af[i]  = *(const bf16x8*)(sA + offA[i]);
    #pragma unroll
    for (int j = 0; j < 4; ++j) bfr[j] = *(const bf16x8*)(sB + offB[j]);
    #pragma unroll
    for (int i = 0; i < 4; ++i)
      #pragma unroll
      for (int j = 0; j < 4; ++j)
        acc[i][j] = __builtin_amdgcn_mfma_f32_16x16x32_bf16(af[i], bfr[j], acc[i][j], 0, 0, 0);
  }

  #pragma unroll
  for (int j = 0; j < 4; ++j) {
    const int col = bn + wn + j*16 + lr;
    const float bv = bias[col];
    #pragma unroll
    for (int i = 0; i < 4; ++i)
      #pragma unroll
      for (int r = 0; r < 4; ++r) {
        const int row = bm + wm + i*16 + lq*4 + r;
        C[(size_t)row * N + col] = acc[i][j][r] + bv;
      }
  }
}

// ---------------- sequential scan: state = silu(state + u_t), fp32 ----------------
__global__ void scan_k(const float* __restrict__ upd, const float* __restrict__ init,
                       bf16* __restrict__ states) {
  const int b = blockIdx.x, s = threadIdx.x;
  const float* u = upd + (size_t)b * SEQ * DSZ + s;
  bf16* st = states + (size_t)b * SEQ * DSZ + s;
  float state = init[s];
  float ubuf[16];
  #pragma unroll
  for (int i = 0; i < 16; ++i) ubuf[i] = u[(size_t)i * DSZ];
  for (int t0 = 0; t0 < SEQ; t0 += 16) {
    #pragma unroll
    for (int i = 0; i < 16; ++i) {
      const int t = t0 + i;
      const float x = state + ubuf[i];
      state = silu_f(x);
      st[(size_t)t * DSZ] = (bf16)state;
      const int tn = t + 16;
      ubuf[i] = (tn < SEQ) ? u[(size_t)tn * DSZ] : 0.0f;
    }
  }
}

extern "C" void kernel_launch(void* const* d_in, const int* in_sizes, int n_in,
                              void* d_out, int out_size, void* d_ws, size_t ws_size,
                              hipStream_t stream) {
  const float* x       = (const float*)d_in[0];
  const float* W_in    = (const float*)d_in[1];
  const float* b_in    = (const float*)d_in[2];
  const float* W_state = (const float*)d_in[3];
  const float* b_state = (const float*)d_in[4];
  const float* W_out   = (const float*)d_in[5];
  const float* b_out   = (const float*)d_in[6];
  const float* init_st = (const float*)d_in[7];
  float* out = (float*)d_out;

  char* ws = (char*)d_ws;
  float* upd        = (float*)(ws + 0);          // 16MB [16384][256] fp32
  bf16*  states_b   = (bf16*)(ws + 16777216);    // 8MB  [16384][256] bf16
  f16*   w_in_t_h   = (f16*)(ws + 25165824);     // 4MB  [2048][1024]
  f16*   w_in_t_l   = (f16*)(ws + 29360128);     // 4MB
  f16*   w_state_t_h= (f16*)(ws + 33554432);     // 1MB  [256][2048]
  f16*   w_state_t_l= (f16*)(ws + 34603008);     // 1MB
  bf16*  w_out_t    = (bf16*)(ws + 35651584);    // 0.5MB [1024][256]
  f16*   xproj_h    = (f16*)(ws + 36175872);     // 64MB [16384][2048]
  f16*   xproj_l    = (f16*)(ws + 103284736);    // 64MB  (end ~162.5MB)

  dim3 tb(32, 8);
  transpose_split_k<<<dim3(DE/32,  DM/32), tb, 0, stream>>>(W_in,    w_in_t_h,    w_in_t_l,    DM,  DE);
  transpose_split_k<<<dim3(DSZ/32, DE/32), tb, 0, stream>>>(W_state, w_state_t_h, w_state_t_l, DE,  DSZ);
  transpose_cast_k <<<dim3(DM/32,  DSZ/32), tb, 0, stream>>>(W_out,  w_out_t,     DSZ, DM);

  // xproj = silu(x @ W_in + b_in) -> hi/lo f16
  gemm1_k<<<dim3(DE/128, MROWS/128), 256, 32768, stream>>>(x, w_in_t_h, w_in_t_l, b_in, xproj_h, xproj_l);

  // upd = xproj @ W_state + b_state -> fp32
  gemm2_k<<<dim3(DSZ/128, MROWS/128), 256, 32768, stream>>>(xproj_h, xproj_l, w_state_t_h, w_state_t_l,
                                                            b_state, upd, DSZ, DE);

  // sequential scan (fp32), emit states as bf16
  scan_k<<<BATCH, DSZ, 0, stream>>>(upd, init_st, states_b);

  // out = states @ W_out + b_out -> fp32
  gemm3_k<<<dim3(DM/128, MROWS/128), 256, 16384, stream>>>(states_b, w_out_t, b_out, out, DM, DSZ);
}